// Round 4
// baseline (174.761 us; speedup 1.0000x reference)
//
#include <hip/hip_runtime.h>
#include <hip/hip_bf16.h>

typedef unsigned short ushort_t;
typedef unsigned short ushortx8 __attribute__((ext_vector_type(8)));
typedef unsigned short ushortx4 __attribute__((ext_vector_type(4)));
typedef __bf16        bf16x8   __attribute__((ext_vector_type(8)));
typedef float         f32x4    __attribute__((ext_vector_type(4)));

#define SCALE_QL (0.29730177875068026f * 1.4426950408889634f) /* 128^-.25 * log2e */
#define OUT_HALF 2097152               /* B*C*H*W elements */
#define NSPLIT   2
#define KT_SPLIT 32                    /* 64 kt tiles / NSPLIT */

static __device__ __forceinline__ float fexp2(float x) {
    float r; asm("v_exp_f32 %0, %1" : "=v"(r) : "v"(x)); return r;
}
static __device__ __forceinline__ float max3f(float a, float b, float c) {
    float r; asm("v_max3_f32 %0, %1, %2, %3" : "=v"(r) : "v"(a), "v"(b), "v"(c));
    return r;
}
static __device__ __forceinline__ unsigned cvtpk_bf16(float lo, float hi) {
    unsigned r;
    asm("v_cvt_pk_bf16_f32 %0, %1, %2" : "=v"(r) : "v"(lo), "v"(hi));
    return r;
}
static __device__ __forceinline__ ushort_t bf16u(float f) {
    __hip_bfloat16 h = __float2bfloat16(f);
    return __builtin_bit_cast(ushort_t, h);
}
static __device__ __forceinline__ void glds16(const void* g, void* l) {
    __builtin_amdgcn_global_load_lds(
        (const __attribute__((address_space(1))) unsigned int*)g,
        (__attribute__((address_space(3))) unsigned int*)l, 16, 0, 0);
}

// ---------------------------------------------------------------------------
// prep: pe [n][d][h] -> pet [h][n][d] f32;  wq/wk/wv f32 -> wb bf16 with
// row-local 16B-chunk xor swizzle (chunk ^= o&15) baked in.
__global__ __launch_bounds__(256) void prep_kernel(
    const float* __restrict__ pe,
    const float* __restrict__ wq, const float* __restrict__ wk,
    const float* __restrict__ wv,
    float* __restrict__ pet, ushort_t* __restrict__ wb)
{
    const int bid = blockIdx.x, t = threadIdx.x;
    if (bid < 1024) {
        int idx = bid * 256 + t;
        float2 p2 = *(const float2*)(pe + (size_t)idx * 2);
        pet[idx]                     = p2.x;
        pet[(size_t)4096 * 64 + idx] = p2.y;
        return;
    }
    const int b2 = bid - 1024;                 // 0..23
    const int p  = b2 >> 3;
    const float* w = (p == 0) ? wq : (p == 1) ? wk : wv;
    const int cid = (b2 & 7) * 256 + t;        // 16B-chunk id 0..2047
    const int o = cid >> 4, chunk = cid & 15;
    float4 f0 = *(const float4*)(w + o * 128 + chunk * 8);
    float4 f1 = *(const float4*)(w + o * 128 + chunk * 8 + 4);
    ushortx8 u;
    u[0] = bf16u(f0.x); u[1] = bf16u(f0.y); u[2] = bf16u(f0.z); u[3] = bf16u(f0.w);
    u[4] = bf16u(f1.x); u[5] = bf16u(f1.y); u[6] = bf16u(f1.z); u[7] = bf16u(f1.w);
    *(ushortx8*)(wb + p * 16384 + o * 128 + ((chunk ^ (o & 15)) << 3)) = u;
}

// ---------------------------------------------------------------------------
// x [b][c=128][n] f32 -> xtb [b][n][c=128] bf16, chunk-swizzled per row.
__global__ __launch_bounds__(256) void xt_kernel(const float* __restrict__ x,
                                                 ushort_t* __restrict__ xtb)
{
    const int nt = blockIdx.x, b = blockIdx.y;
    __shared__ __align__(16) ushort_t xs[128][68];
    const int t = threadIdx.x;
    const int cg = t >> 4, n0 = (t & 15) * 4;
#pragma unroll
    for (int i = 0; i < 8; ++i) {
        int c = i * 16 + cg;
        float4 f = *(const float4*)(x + ((size_t)(b * 128 + c)) * 4096 + nt * 64 + n0);
        ushortx4 u;
        u[0] = bf16u(f.x); u[1] = bf16u(f.y); u[2] = bf16u(f.z); u[3] = bf16u(f.w);
        *(ushortx4*)(&xs[c][n0]) = u;
    }
    __syncthreads();
    const int n = t >> 2;
    ushort_t* dst = xtb + ((size_t)b * 4096 + nt * 64 + n) * 128;
#pragma unroll
    for (int j = 0; j < 4; ++j) {
        int chunk = (t & 3) * 4 + j;
        ushortx8 u;
#pragma unroll
        for (int e = 0; e < 8; ++e) u[e] = xs[chunk * 8 + e][n];
        *(ushortx8*)(dst + ((chunk ^ (n & 15)) << 3)) = u;
    }
}

// ---------------------------------------------------------------------------
// MFMA projection: per block 128 outputs x 128 tokens, K=128.
// grid (32 ntile, 4 b, 3 p), 256 thr (4 waves, each 32 output rows).
__global__ __launch_bounds__(256, 2) void proj_kernel(
    const ushort_t* __restrict__ xtb, const ushort_t* __restrict__ wb,
    const float* __restrict__ bq, const float* __restrict__ bk,
    const float* __restrict__ bv, const float* __restrict__ pet,
    ushort_t* __restrict__ qw, ushort_t* __restrict__ kw,
    ushort_t* __restrict__ vw)
{
    const int ntl = blockIdx.x;        // 128-token tile
    const int b = blockIdx.y, p = blockIdx.z;
    __shared__ __align__(16) ushort_t xt[16384];   // [n128][c128] swizzled
    __shared__ __align__(16) ushort_t wt[16384];   // [o128][c128] swizzled
    const int t = threadIdx.x, lane = t & 63;
    const int wv_ = __builtin_amdgcn_readfirstlane(t >> 6);
    const int l16 = lane & 15, lhi = lane >> 4;

    const ushort_t* xsrc = xtb + ((size_t)b * 4096 + ntl * 128) * 128;
    const ushort_t* wsrc = wb + p * 16384;
#pragma unroll
    for (int j = 0; j < 8; ++j) {
        int row = wv_ * 32 + j * 4;
        glds16(xsrc + row * 128 + lane * 8, xt + row * 128);
        glds16(wsrc + row * 128 + lane * 8, wt + row * 128);
    }

    const float* bias = (p == 0) ? bq : (p == 1) ? bk : bv;
    f32x4 bias4[2];
    bias4[0] = *(const f32x4*)(bias + wv_ * 32 + lhi * 4);
    bias4[1] = *(const f32x4*)(bias + wv_ * 32 + 16 + lhi * 4);
    f32x4 acc[2][8];
#pragma unroll
    for (int mf = 0; mf < 2; ++mf)
#pragma unroll
        for (int nf = 0; nf < 8; ++nf) acc[mf][nf] = bias4[mf];

    __syncthreads();

    const char* xbp = (const char*)xt;
    const char* wbp = (const char*)wt;
#pragma unroll
    for (int ks = 0; ks < 4; ++ks) {
        bf16x8 af[2];
#pragma unroll
        for (int mf = 0; mf < 2; ++mf) {
            int row = wv_ * 32 + mf * 16 + l16;
            af[mf] = __builtin_bit_cast(bf16x8, *(const ushortx8*)(
                wbp + row * 256 + ((((ks * 4 + lhi) ^ l16) & 15) << 4)));
        }
#pragma unroll
        for (int nf = 0; nf < 8; ++nf) {
            int row = nf * 16 + l16;
            bf16x8 bfr = __builtin_bit_cast(bf16x8, *(const ushortx8*)(
                xbp + row * 256 + ((((ks * 4 + lhi) ^ l16) & 15) << 4)));
            acc[0][nf] = __builtin_amdgcn_mfma_f32_16x16x32_bf16(af[0], bfr, acc[0][nf], 0, 0, 0);
            acc[1][nf] = __builtin_amdgcn_mfma_f32_16x16x32_bf16(af[1], bfr, acc[1][nf], 0, 0, 0);
        }
    }

    const int nbase = ntl * 128;
    if (p == 2) {                      // V -> d-major [bh][d][n]
#pragma unroll
        for (int mf = 0; mf < 2; ++mf) {
            int o = wv_ * 32 + mf * 16 + lhi * 4;
            int h = o >> 6, d = o & 63;
            ushort_t* vb = vw + (((size_t)(b * 2 + h) * 64 + d)) * 4096 + nbase + l16;
#pragma unroll
            for (int nf = 0; nf < 8; ++nf)
#pragma unroll
                for (int r = 0; r < 4; ++r)
                    vb[(size_t)r * 4096 + nf * 16] = bf16u(acc[mf][nf][r]);
        }
    } else if (p == 0) {               // Q: +pe, *scale, token-major
#pragma unroll
        for (int mf = 0; mf < 2; ++mf) {
            int o = wv_ * 32 + mf * 16 + lhi * 4;
            int h = o >> 6, d = o & 63;
#pragma unroll
            for (int nf = 0; nf < 8; ++nf) {
                int n = nbase + nf * 16 + l16;
                f32x4 pe4 = *(const f32x4*)(pet + ((size_t)h * 4096 + n) * 64 + d);
                f32x4 q4 = (acc[mf][nf] + pe4) * SCALE_QL;
                ushortx4 s;
                s[0] = bf16u(q4[0]); s[1] = bf16u(q4[1]);
                s[2] = bf16u(q4[2]); s[3] = bf16u(q4[3]);
                *(ushortx4*)(qw + ((size_t)(b * 2 + h) * 4096 + n) * 64 + d) = s;
            }
        }
    } else {                           // K: token-major
#pragma unroll
        for (int mf = 0; mf < 2; ++mf) {
            int o = wv_ * 32 + mf * 16 + lhi * 4;
            int h = o >> 6, d = o & 63;
#pragma unroll
            for (int nf = 0; nf < 8; ++nf) {
                int n = nbase + nf * 16 + l16;
                f32x4 k4 = acc[mf][nf];
                ushortx4 s;
                s[0] = bf16u(k4[0]); s[1] = bf16u(k4[1]);
                s[2] = bf16u(k4[2]); s[3] = bf16u(k4[3]);
                *(ushortx4*)(kw + ((size_t)(b * 2 + h) * 4096 + n) * 64 + d) = s;
            }
        }
    }
}

// ---------------------------------------------------------------------------
// Flash attention, swapped-operand (S^T = K*Q), K LDS double-buffered with
// prefetch, V direct global->reg, defer-max, 1 barrier/iter.
// grid (64 qtile, 8 bh, NSPLIT), 256 thr (4 waves x 16 q-rows).
__global__ __launch_bounds__(256, 4) void attn_kernel(
    const ushort_t* __restrict__ qw, const ushort_t* __restrict__ kw,
    const ushort_t* __restrict__ vw, float* __restrict__ opart,
    float* __restrict__ mlpart)
{
    const int qt = blockIdx.x, bh = blockIdx.y, sp = blockIdx.z;
    const int t = threadIdx.x, lane = t & 63;
    const int wvid = t >> 6;
    const int l16 = lane & 15, lhi = lane >> 4;

    __shared__ __align__(16) ushort_t Kt[2 * 64 * 64];   // dbuf [key][d] swizzled
    __shared__ __align__(16) unsigned PtW[4 * 16 * 36];  // per-wave P exchange

    // Q fragment (B operand): col = q = l16, k = d chunk lhi*8 (+32)
    const ushort_t* qp =
        qw + (((size_t)bh * 4096) + qt * 64 + wvid * 16 + l16) * 64 + lhi * 8;
    const bf16x8 bq0 = __builtin_bit_cast(bf16x8, *(const ushortx8*)(qp));
    const bf16x8 bq1 = __builtin_bit_cast(bf16x8, *(const ushortx8*)(qp + 32));

    const ushort_t* kgb = kw + ((size_t)bh * 4096) * 64;
    const ushort_t* vgb = vw + ((size_t)bh * 64) * 4096;

    // K staging: lane covers rows rb+sub, rb+8+sub; source pre-XOR-swizzled.
    const int sub = lane >> 3, c7 = lane & 7;
    const int rb  = wvid * 16;
    const int swz = (c7 ^ sub) << 3;
    const size_t koff0 = (size_t)(rb + sub) * 64 + swz;
    const size_t koff1 = (size_t)(rb + 8 + sub) * 64 + swz;

    // swizzled read offset: chunk lhi of row (16c+l16) sits at byte xs0
    const int xs0 = (lhi ^ (l16 & 7)) << 4;
    const int xs1 = xs0 ^ 64;

    float m = -1e30f, lsum = 0.f;
    f32x4 oacc[4];
    const f32x4 fz = {0.f, 0.f, 0.f, 0.f};
#pragma unroll
    for (int dc = 0; dc < 4; ++dc) oacc[dc] = fz;

    const int kt0 = sp * KT_SPLIT, ktend = kt0 + KT_SPLIT;

    // prologue: stage K(kt0) into buf 0
    {
        const ushort_t* kg = kgb + (size_t)kt0 * 4096;
        glds16(kg + koff0, Kt + (size_t)(rb) * 64);
        glds16(kg + koff1, Kt + (size_t)(rb + 8) * 64);
    }
    __syncthreads();

    int cur = 0;
    for (int kt = kt0; kt < ktend; ++kt) {
        // --- prefetch next K tile into the other buffer (no wait) ---
        {
            int ktn = (kt + 1 < ktend) ? kt + 1 : kt;
            const ushort_t* kg = kgb + (size_t)ktn * 4096;
            ushort_t* kd = Kt + (cur ^ 1) * 4096;
            glds16(kg + koff0, kd + (size_t)rb * 64);
            glds16(kg + koff1, kd + (size_t)(rb + 8) * 64);
        }
        // --- V fragments for current tile: direct global->reg ---
        const ushort_t* vg = vgb + (size_t)kt * 64;
        ushortx8 vf[8];
#pragma unroll
        for (int dc = 0; dc < 4; ++dc) {
            const ushort_t* vr = vg + (size_t)(dc * 16 + l16) * 4096 + lhi * 8;
            vf[2 * dc]     = *(const ushortx8*)(vr);
            vf[2 * dc + 1] = *(const ushortx8*)(vr + 32);
        }

        // --- S^T = K * Q ---
        const char* kcb = (const char*)Kt + cur * 8192;
        f32x4 sacc[4];
        __builtin_amdgcn_s_setprio(1);
#pragma unroll
        for (int kc = 0; kc < 4; ++kc) {
            const int row = kc * 16 + l16;
            bf16x8 ka0 = __builtin_bit_cast(bf16x8,
                *(const ushortx8*)(kcb + row * 128 + xs0));
            bf16x8 ka1 = __builtin_bit_cast(bf16x8,
                *(const ushortx8*)(kcb + row * 128 + xs1));
            f32x4 z = fz;
            z = __builtin_amdgcn_mfma_f32_16x16x32_bf16(ka0, bq0, z, 0, 0, 0);
            z = __builtin_amdgcn_mfma_f32_16x16x32_bf16(ka1, bq1, z, 0, 0, 0);
            sacc[kc] = z;
        }
        __builtin_amdgcn_s_setprio(0);

        // --- lane-local online softmax (log2 domain), defer-max THR=8 ---
        float smax;
        {
            float a = max3f(sacc[0][0], sacc[0][1], sacc[0][2]);
            float b = max3f(sacc[0][3], sacc[1][0], sacc[1][1]);
            float c = max3f(sacc[1][2], sacc[1][3], sacc[2][0]);
            float d = max3f(sacc[2][1], sacc[2][2], sacc[2][3]);
            float e = max3f(sacc[3][0], sacc[3][1], sacc[3][2]);
            smax = fmaxf(max3f(a, b, c), max3f(d, e, sacc[3][3]));
        }
        smax = fmaxf(smax, __shfl_xor(smax, 16, 64));
        smax = fmaxf(smax, __shfl_xor(smax, 32, 64));

        if (!__all(smax - m <= 8.0f)) {          // wave-uniform rescale
            float mnew = fmaxf(m, smax);
            float corr = fexp2(m - mnew);
            m = mnew;
            lsum *= corr;
#pragma unroll
            for (int dc = 0; dc < 4; ++dc) oacc[dc] *= corr;
        }

        float p[16], psum = 0.f;
#pragma unroll
        for (int kc = 0; kc < 4; ++kc)
#pragma unroll
            for (int r = 0; r < 4; ++r) {
                float pp = fexp2(sacc[kc][r] - m);
                p[kc * 4 + r] = pp;
                psum += pp;
            }
        psum += __shfl_xor(psum, 16, 64);
        psum += __shfl_xor(psum, 32, 64);
        lsum += psum;

        // --- P exchange: 4 x ds_write_b64 + 2 x ds_read_b128 per lane ---
        unsigned* prow = PtW + wvid * 576 + l16 * 36;
#pragma unroll
        for (int kc = 0; kc < 4; ++kc) {
            uint2 w2;
            w2.x = cvtpk_bf16(p[kc * 4 + 0], p[kc * 4 + 1]);
            w2.y = cvtpk_bf16(p[kc * 4 + 2], p[kc * 4 + 3]);
            *(uint2*)(prow + 8 * kc + 2 * lhi) = w2;
        }
        uint4 r0 = *(uint4*)(prow + 4 * lhi);
        uint4 r1 = *(uint4*)(prow + 16 + 4 * lhi);
        bf16x8 pb0 = __builtin_bit_cast(bf16x8, r0);
        bf16x8 pb1 = __builtin_bit_cast(bf16x8, r1);

        // --- O^T += V^T P^T (V from registers) ---
        __builtin_amdgcn_s_setprio(1);
#pragma unroll
        for (int dc = 0; dc < 4; ++dc) {
            bf16x8 va0 = __builtin_bit_cast(bf16x8, vf[2 * dc]);
            bf16x8 va1 = __builtin_bit_cast(bf16x8, vf[2 * dc + 1]);
            oacc[dc] = __builtin_amdgcn_mfma_f32_16x16x32_bf16(va0, pb0, oacc[dc], 0, 0, 0);
            oacc[dc] = __builtin_amdgcn_mfma_f32_16x16x32_bf16(va1, pb1, oacc[dc], 0, 0, 0);
        }
        __builtin_amdgcn_s_setprio(0);

        __syncthreads();                 // drains prefetch glds + orders dbuf
        cur ^= 1;
    }

    // partial epilogue: lane-major coalesced dump; combine kernel unpicks it
    const int pidx = (qt * 8 + bh) * NSPLIT + sp;
    float* op = opart + (size_t)pidx * 4096 + wvid * 1024 + lane * 16;
#pragma unroll
    for (int dc = 0; dc < 4; ++dc) *(f32x4*)(op + dc * 4) = oacc[dc];
    if (lhi == 0) {
        float* mlo = mlpart + (size_t)pidx * 128 + wvid * 32 + l16;
        mlo[0]  = m;
        mlo[16] = lsum;
    }
}

// ---------------------------------------------------------------------------
// Combine NSPLIT partials, normalize, transpose, write out twice.
__global__ __launch_bounds__(256) void combine_kernel(
    const float* __restrict__ opart, const float* __restrict__ mlpart,
    float* __restrict__ out)
{
    const int qt = blockIdx.x, bh = blockIdx.y;
    const int b = bh >> 1, h = bh & 1;
    const int t = threadIdx.x, lane = t & 63, w = t >> 6;
    const int l16 = lane & 15, lhi = lane >> 4;
    __shared__ __align__(16) float smT[64][68];

    const int p0 = (qt * 8 + bh) * NSPLIT;
    const float* mlb = mlpart + (size_t)p0 * 128 + w * 32 + l16;
    float m1 = mlb[0],   l1 = mlb[16];
    float m2 = mlb[128], l2 = mlb[128 + 16];
    float M  = fmaxf(m1, m2);
    float c1 = fexp2(m1 - M), c2 = fexp2(m2 - M);
    float inv = 1.f / (l1 * c1 + l2 * c2);
    c1 *= inv; c2 *= inv;

    const float* o1 = opart + (size_t)p0 * 4096 + w * 1024 + lane * 16;
    const float* o2 = o1 + 4096;
#pragma unroll
    for (int dc = 0; dc < 4; ++dc) {
        f32x4 a  = *(const f32x4*)(o1 + dc * 4);
        f32x4 bb = *(const f32x4*)(o2 + dc * 4);
        f32x4 ov = a * c1 + bb * c2;
#pragma unroll
        for (int r = 0; r < 4; ++r)
            smT[dc * 16 + lhi * 4 + r][w * 16 + l16] = ov[r];
    }
    __syncthreads();

    const int d = t >> 2, qq = t & 3;
    size_t ob = (((size_t)(b * 64 + d)) * 2 + h) * 4096 + qt * 64 + qq * 16;
#pragma unroll
    for (int k0 = 0; k0 < 16; k0 += 4) {
        f32x4 vv = *(const f32x4*)(&smT[d][qq * 16 + k0]);
        *(f32x4*)(out + ob + k0) = vv;
        *(f32x4*)(out + ob + OUT_HALF + k0) = vv;
    }
}

// ---------------------------------------------------------------------------
extern "C" void kernel_launch(void* const* d_in, const int* in_sizes, int n_in,
                              void* d_out, int out_size, void* d_ws, size_t ws_size,
                              hipStream_t stream) {
    const float* x  = (const float*)d_in[0];
    const float* wq = (const float*)d_in[1];
    const float* bq = (const float*)d_in[2];
    const float* wk = (const float*)d_in[3];
    const float* bk = (const float*)d_in[4];
    const float* wv = (const float*)d_in[5];
    const float* bv = (const float*)d_in[6];
    const float* pe = (const float*)d_in[7];
    float* out = (float*)d_out;

    char* ws = (char*)d_ws;
    float*    pet   = (float*)ws;                                   // 2 MB
    ushort_t* qw    = (ushort_t*)(ws + (size_t)2  * 1024 * 1024);   // 4 MB
    ushort_t* kw    = (ushort_t*)(ws + (size_t)6  * 1024 * 1024);   // 4 MB
    ushort_t* vw    = (ushort_t*)(ws + (size_t)10 * 1024 * 1024);   // 4 MB
    float*    opart = (float*)(ws + (size_t)14 * 1024 * 1024);      // 16 MB (attn)
    ushort_t* xtb   = (ushort_t*)(ws + (size_t)14 * 1024 * 1024);   // 4 MB (proj, aliases opart)
    float*    mlprt = (float*)(ws + (size_t)30 * 1024 * 1024);      // 0.5 MB (attn)
    ushort_t* wb    = (ushort_t*)(ws + (size_t)30 * 1024 * 1024);   // 96 KB (proj, aliases mlprt)

    hipLaunchKernelGGL(prep_kernel, dim3(1048), dim3(256), 0, stream,
                       pe, wq, wk, wv, pet, wb);
    hipLaunchKernelGGL(xt_kernel, dim3(64, 4), dim3(256), 0, stream, x, xtb);
    hipLaunchKernelGGL(proj_kernel, dim3(32, 4, 3), dim3(256), 0, stream,
                       xtb, wb, bq, bk, bv, pet, qw, kw, vw);
    hipLaunchKernelGGL(attn_kernel, dim3(64, 8, NSPLIT), dim3(256), 0, stream,
                       qw, kw, vw, opart, mlprt);
    hipLaunchKernelGGL(combine_kernel, dim3(64, 8), dim3(256), 0, stream,
                       opart, mlprt, out);
}

// Round 5
// 116.728 us; speedup vs baseline: 1.4972x; 1.4972x over previous
//
#include <hip/hip_runtime.h>
#include <hip/hip_bf16.h>

typedef unsigned short ushort_t;
typedef unsigned short ushortx8 __attribute__((ext_vector_type(8)));
typedef unsigned short ushortx4 __attribute__((ext_vector_type(4)));
typedef __bf16        bf16x8   __attribute__((ext_vector_type(8)));
typedef float         f32x4    __attribute__((ext_vector_type(4)));

#define SCALE_QL (0.29730177875068026f * 1.4426950408889634f) /* 128^-.25 * log2e */
#define OUT_HALF 2097152               /* B*C*H*W elements */
#define NSPLIT   2
#define KT_SPLIT 32                    /* 64 kt tiles / NSPLIT */

static __device__ __forceinline__ float fexp2(float x) {
    float r; asm("v_exp_f32 %0, %1" : "=v"(r) : "v"(x)); return r;
}
static __device__ __forceinline__ float max3f(float a, float b, float c) {
    float r; asm("v_max3_f32 %0, %1, %2, %3" : "=v"(r) : "v"(a), "v"(b), "v"(c));
    return r;
}
static __device__ __forceinline__ unsigned cvtpk_bf16(float lo, float hi) {
    unsigned r;
    asm("v_cvt_pk_bf16_f32 %0, %1, %2" : "=v"(r) : "v"(lo), "v"(hi));
    return r;
}
static __device__ __forceinline__ ushort_t bf16u(float f) {
    __hip_bfloat16 h = __float2bfloat16(f);
    return __builtin_bit_cast(ushort_t, h);
}
static __device__ __forceinline__ void glds16(const void* g, void* l) {
    __builtin_amdgcn_global_load_lds(
        (const __attribute__((address_space(1))) unsigned int*)g,
        (__attribute__((address_space(3))) unsigned int*)l, 16, 0, 0);
}

// ---------------------------------------------------------------------------
// prep: pe [n][d][h] -> pet [h][n][d] f32;  wq/wk/wv f32 -> wb bf16 with
// row-local 16B-chunk xor swizzle (chunk ^= o&15) baked in.
__global__ __launch_bounds__(256) void prep_kernel(
    const float* __restrict__ pe,
    const float* __restrict__ wq, const float* __restrict__ wk,
    const float* __restrict__ wv,
    float* __restrict__ pet, ushort_t* __restrict__ wb)
{
    const int bid = blockIdx.x, t = threadIdx.x;
    if (bid < 1024) {
        int idx = bid * 256 + t;
        float2 p2 = *(const float2*)(pe + (size_t)idx * 2);
        pet[idx]                     = p2.x;
        pet[(size_t)4096 * 64 + idx] = p2.y;
        return;
    }
    const int b2 = bid - 1024;                 // 0..23
    const int p  = b2 >> 3;
    const float* w = (p == 0) ? wq : (p == 1) ? wk : wv;
    const int cid = (b2 & 7) * 256 + t;        // 16B-chunk id 0..2047
    const int o = cid >> 4, chunk = cid & 15;
    float4 f0 = *(const float4*)(w + o * 128 + chunk * 8);
    float4 f1 = *(const float4*)(w + o * 128 + chunk * 8 + 4);
    ushortx8 u;
    u[0] = bf16u(f0.x); u[1] = bf16u(f0.y); u[2] = bf16u(f0.z); u[3] = bf16u(f0.w);
    u[4] = bf16u(f1.x); u[5] = bf16u(f1.y); u[6] = bf16u(f1.z); u[7] = bf16u(f1.w);
    *(ushortx8*)(wb + p * 16384 + o * 128 + ((chunk ^ (o & 15)) << 3)) = u;
}

// ---------------------------------------------------------------------------
// x [b][c=128][n] f32 -> xtb [b][n][c=128] bf16, chunk-swizzled per row.
__global__ __launch_bounds__(256) void xt_kernel(const float* __restrict__ x,
                                                 ushort_t* __restrict__ xtb)
{
    const int nt = blockIdx.x, b = blockIdx.y;
    __shared__ __align__(16) ushort_t xs[128][68];
    const int t = threadIdx.x;
    const int cg = t >> 4, n0 = (t & 15) * 4;
#pragma unroll
    for (int i = 0; i < 8; ++i) {
        int c = i * 16 + cg;
        float4 f = *(const float4*)(x + ((size_t)(b * 128 + c)) * 4096 + nt * 64 + n0);
        ushortx4 u;
        u[0] = bf16u(f.x); u[1] = bf16u(f.y); u[2] = bf16u(f.z); u[3] = bf16u(f.w);
        *(ushortx4*)(&xs[c][n0]) = u;
    }
    __syncthreads();
    const int n = t >> 2;
    ushort_t* dst = xtb + ((size_t)b * 4096 + nt * 64 + n) * 128;
#pragma unroll
    for (int j = 0; j < 4; ++j) {
        int chunk = (t & 3) * 4 + j;
        ushortx8 u;
#pragma unroll
        for (int e = 0; e < 8; ++e) u[e] = xs[chunk * 8 + e][n];
        *(ushortx8*)(dst + ((chunk ^ (n & 15)) << 3)) = u;
    }
}

// ---------------------------------------------------------------------------
// MFMA projection: per block 128 outputs x 128 tokens, K=128.
// grid (32 ntile, 4 b, 3 p), 256 thr (4 waves, each 32 output rows).
__global__ __launch_bounds__(256, 2) void proj_kernel(
    const ushort_t* __restrict__ xtb, const ushort_t* __restrict__ wb,
    const float* __restrict__ bq, const float* __restrict__ bk,
    const float* __restrict__ bv, const float* __restrict__ pet,
    ushort_t* __restrict__ qw, ushort_t* __restrict__ kw,
    ushort_t* __restrict__ vw)
{
    const int ntl = blockIdx.x;        // 128-token tile
    const int b = blockIdx.y, p = blockIdx.z;
    __shared__ __align__(16) ushort_t xt[16384];   // [n128][c128] swizzled
    __shared__ __align__(16) ushort_t wt[16384];   // [o128][c128] swizzled
    const int t = threadIdx.x, lane = t & 63;
    const int wv_ = __builtin_amdgcn_readfirstlane(t >> 6);
    const int l16 = lane & 15, lhi = lane >> 4;

    const ushort_t* xsrc = xtb + ((size_t)b * 4096 + ntl * 128) * 128;
    const ushort_t* wsrc = wb + p * 16384;
#pragma unroll
    for (int j = 0; j < 8; ++j) {
        int row = wv_ * 32 + j * 4;
        glds16(xsrc + row * 128 + lane * 8, xt + row * 128);
        glds16(wsrc + row * 128 + lane * 8, wt + row * 128);
    }

    const float* bias = (p == 0) ? bq : (p == 1) ? bk : bv;
    f32x4 bias4[2];
    bias4[0] = *(const f32x4*)(bias + wv_ * 32 + lhi * 4);
    bias4[1] = *(const f32x4*)(bias + wv_ * 32 + 16 + lhi * 4);
    f32x4 acc[2][8];
#pragma unroll
    for (int mf = 0; mf < 2; ++mf)
#pragma unroll
        for (int nf = 0; nf < 8; ++nf) acc[mf][nf] = bias4[mf];

    __syncthreads();

    const char* xbp = (const char*)xt;
    const char* wbp = (const char*)wt;
#pragma unroll
    for (int ks = 0; ks < 4; ++ks) {
        bf16x8 af[2];
#pragma unroll
        for (int mf = 0; mf < 2; ++mf) {
            int row = wv_ * 32 + mf * 16 + l16;
            af[mf] = __builtin_bit_cast(bf16x8, *(const ushortx8*)(
                wbp + row * 256 + ((((ks * 4 + lhi) ^ l16) & 15) << 4)));
        }
#pragma unroll
        for (int nf = 0; nf < 8; ++nf) {
            int row = nf * 16 + l16;
            bf16x8 bfr = __builtin_bit_cast(bf16x8, *(const ushortx8*)(
                xbp + row * 256 + ((((ks * 4 + lhi) ^ l16) & 15) << 4)));
            acc[0][nf] = __builtin_amdgcn_mfma_f32_16x16x32_bf16(af[0], bfr, acc[0][nf], 0, 0, 0);
            acc[1][nf] = __builtin_amdgcn_mfma_f32_16x16x32_bf16(af[1], bfr, acc[1][nf], 0, 0, 0);
        }
    }

    const int nbase = ntl * 128;
    if (p == 2) {                      // V -> d-major [bh][d][n]
#pragma unroll
        for (int mf = 0; mf < 2; ++mf) {
            int o = wv_ * 32 + mf * 16 + lhi * 4;
            int h = o >> 6, d = o & 63;
            ushort_t* vb = vw + (((size_t)(b * 2 + h) * 64 + d)) * 4096 + nbase + l16;
#pragma unroll
            for (int nf = 0; nf < 8; ++nf)
#pragma unroll
                for (int r = 0; r < 4; ++r)
                    vb[(size_t)r * 4096 + nf * 16] = bf16u(acc[mf][nf][r]);
        }
    } else if (p == 0) {               // Q: +pe, *scale, token-major
#pragma unroll
        for (int mf = 0; mf < 2; ++mf) {
            int o = wv_ * 32 + mf * 16 + lhi * 4;
            int h = o >> 6, d = o & 63;
#pragma unroll
            for (int nf = 0; nf < 8; ++nf) {
                int n = nbase + nf * 16 + l16;
                f32x4 pe4 = *(const f32x4*)(pet + ((size_t)h * 4096 + n) * 64 + d);
                f32x4 q4 = (acc[mf][nf] + pe4) * SCALE_QL;
                ushortx4 s;
                s[0] = bf16u(q4[0]); s[1] = bf16u(q4[1]);
                s[2] = bf16u(q4[2]); s[3] = bf16u(q4[3]);
                *(ushortx4*)(qw + ((size_t)(b * 2 + h) * 4096 + n) * 64 + d) = s;
            }
        }
    } else {                           // K: token-major
#pragma unroll
        for (int mf = 0; mf < 2; ++mf) {
            int o = wv_ * 32 + mf * 16 + lhi * 4;
            int h = o >> 6, d = o & 63;
#pragma unroll
            for (int nf = 0; nf < 8; ++nf) {
                int n = nbase + nf * 16 + l16;
                f32x4 k4 = acc[mf][nf];
                ushortx4 s;
                s[0] = bf16u(k4[0]); s[1] = bf16u(k4[1]);
                s[2] = bf16u(k4[2]); s[3] = bf16u(k4[3]);
                *(ushortx4*)(kw + ((size_t)(b * 2 + h) * 4096 + n) * 64 + d) = s;
            }
        }
    }
}

// ---------------------------------------------------------------------------
// Flash attention, swapped-operand (S^T = K*Q). K AND V double-buffered in
// LDS, prefetched at iteration top via glds16 (coalesced), one barrier/iter
// so the prefetch latency hides under QK+softmax+PV. defer-max THR=8.
// grid (64 qtile, 8 bh, NSPLIT), 256 thr (4 waves x 16 q-rows).
__global__ __launch_bounds__(256) void attn_kernel(
    const ushort_t* __restrict__ qw, const ushort_t* __restrict__ kw,
    const ushort_t* __restrict__ vw, float* __restrict__ opart,
    float* __restrict__ mlpart)
{
    const int qt = blockIdx.x, bh = blockIdx.y, sp = blockIdx.z;
    const int t = threadIdx.x, lane = t & 63;
    const int wvid = t >> 6;
    const int l16 = lane & 15, lhi = lane >> 4;

    __shared__ __align__(16) ushort_t Kt[2 * 64 * 64];   // dbuf [key][d] swz
    __shared__ __align__(16) ushort_t Vt[2 * 64 * 64];   // dbuf [d][key] swz
    __shared__ __align__(16) unsigned PtW[4 * 16 * 36];  // per-wave P exchange

    // Q fragment (B operand): col = q = l16, k = d chunk lhi*8 (+32)
    const ushort_t* qp =
        qw + (((size_t)bh * 4096) + qt * 64 + wvid * 16 + l16) * 64 + lhi * 8;
    const bf16x8 bq0 = __builtin_bit_cast(bf16x8, *(const ushortx8*)(qp));
    const bf16x8 bq1 = __builtin_bit_cast(bf16x8, *(const ushortx8*)(qp + 32));

    const ushort_t* kgb = kw + ((size_t)bh * 4096) * 64;
    const ushort_t* vgb = vw + ((size_t)bh * 64) * 4096;

    // staging: lane covers rows rb+sub, rb+8+sub; source pre-XOR-swizzled.
    const int sub = lane >> 3, c7 = lane & 7;
    const int rb  = wvid * 16;
    const int swz = (c7 ^ sub) << 3;
    const size_t koff0 = (size_t)(rb + sub) * 64 + swz;
    const size_t koff1 = (size_t)(rb + 8 + sub) * 64 + swz;
    const size_t voff0 = (size_t)(rb + sub) * 4096 + swz;
    const size_t voff1 = (size_t)(rb + 8 + sub) * 4096 + swz;

    // swizzled read offset: chunk lhi of row (16c+l16) sits at byte xs0
    const int xs0 = (lhi ^ (l16 & 7)) << 4;
    const int xs1 = xs0 ^ 64;

    float m = -1e30f, lsum = 0.f;
    f32x4 oacc[4];
    const f32x4 fz = {0.f, 0.f, 0.f, 0.f};
#pragma unroll
    for (int dc = 0; dc < 4; ++dc) oacc[dc] = fz;

    const int kt0 = sp * KT_SPLIT, ktend = kt0 + KT_SPLIT;

    // prologue: stage K,V(kt0) into buf 0
    {
        const ushort_t* kg = kgb + (size_t)kt0 * 4096;
        const ushort_t* vg = vgb + (size_t)kt0 * 64;
        glds16(kg + koff0, Kt + (size_t)rb * 64);
        glds16(kg + koff1, Kt + (size_t)(rb + 8) * 64);
        glds16(vg + voff0, Vt + (size_t)rb * 64);
        glds16(vg + voff1, Vt + (size_t)(rb + 8) * 64);
    }
    __syncthreads();

    int cur = 0;
    for (int kt = kt0; kt < ktend; ++kt) {
        // --- prefetch next K,V tiles into the other buffers (no wait) ---
        {
            int ktn = (kt + 1 < ktend) ? kt + 1 : kt;
            const ushort_t* kg = kgb + (size_t)ktn * 4096;
            const ushort_t* vg = vgb + (size_t)ktn * 64;
            ushort_t* kd = Kt + (cur ^ 1) * 4096;
            ushort_t* vd = Vt + (cur ^ 1) * 4096;
            glds16(kg + koff0, kd + (size_t)rb * 64);
            glds16(kg + koff1, kd + (size_t)(rb + 8) * 64);
            glds16(vg + voff0, vd + (size_t)rb * 64);
            glds16(vg + voff1, vd + (size_t)(rb + 8) * 64);
        }

        // --- S^T = K * Q ---
        const char* kcb = (const char*)Kt + cur * 8192;
        f32x4 sacc[4];
        __builtin_amdgcn_s_setprio(1);
#pragma unroll
        for (int kc = 0; kc < 4; ++kc) {
            const int row = kc * 16 + l16;
            bf16x8 ka0 = __builtin_bit_cast(bf16x8,
                *(const ushortx8*)(kcb + row * 128 + xs0));
            bf16x8 ka1 = __builtin_bit_cast(bf16x8,
                *(const ushortx8*)(kcb + row * 128 + xs1));
            f32x4 z = fz;
            z = __builtin_amdgcn_mfma_f32_16x16x32_bf16(ka0, bq0, z, 0, 0, 0);
            z = __builtin_amdgcn_mfma_f32_16x16x32_bf16(ka1, bq1, z, 0, 0, 0);
            sacc[kc] = z;
        }
        __builtin_amdgcn_s_setprio(0);

        // --- lane-local online softmax (log2 domain), defer-max THR=8 ---
        float smax;
        {
            float a = max3f(sacc[0][0], sacc[0][1], sacc[0][2]);
            float b = max3f(sacc[0][3], sacc[1][0], sacc[1][1]);
            float c = max3f(sacc[1][2], sacc[1][3], sacc[2][0]);
            float d = max3f(sacc[2][1], sacc[2][2], sacc[2][3]);
            float e = max3f(sacc[3][0], sacc[3][1], sacc[3][2]);
            smax = fmaxf(max3f(a, b, c), max3f(d, e, sacc[3][3]));
        }
        smax = fmaxf(smax, __shfl_xor(smax, 16, 64));
        smax = fmaxf(smax, __shfl_xor(smax, 32, 64));

        if (!__all(smax - m <= 8.0f)) {          // wave-uniform rescale
            float mnew = fmaxf(m, smax);
            float corr = fexp2(m - mnew);
            m = mnew;
            lsum *= corr;
#pragma unroll
            for (int dc = 0; dc < 4; ++dc) oacc[dc] *= corr;
        }

        float p[16], psum = 0.f;
#pragma unroll
        for (int kc = 0; kc < 4; ++kc)
#pragma unroll
            for (int r = 0; r < 4; ++r) {
                float pp = fexp2(sacc[kc][r] - m);
                p[kc * 4 + r] = pp;
                psum += pp;
            }
        psum += __shfl_xor(psum, 16, 64);
        psum += __shfl_xor(psum, 32, 64);
        lsum += psum;

        // --- P exchange: 4 x ds_write_b64 + 2 x ds_read_b128 per lane ---
        unsigned* prow = PtW + wvid * 576 + l16 * 36;
#pragma unroll
        for (int kc = 0; kc < 4; ++kc) {
            uint2 w2;
            w2.x = cvtpk_bf16(p[kc * 4 + 0], p[kc * 4 + 1]);
            w2.y = cvtpk_bf16(p[kc * 4 + 2], p[kc * 4 + 3]);
            *(uint2*)(prow + 8 * kc + 2 * lhi) = w2;
        }
        uint4 r0 = *(uint4*)(prow + 4 * lhi);
        uint4 r1 = *(uint4*)(prow + 16 + 4 * lhi);
        bf16x8 pb0 = __builtin_bit_cast(bf16x8, r0);
        bf16x8 pb1 = __builtin_bit_cast(bf16x8, r1);

        // --- O^T += V^T P^T ---
        const char* vcb = (const char*)Vt + cur * 8192;
        __builtin_amdgcn_s_setprio(1);
#pragma unroll
        for (int dc = 0; dc < 4; ++dc) {
            const int row = dc * 16 + l16;
            bf16x8 va0 = __builtin_bit_cast(bf16x8,
                *(const ushortx8*)(vcb + row * 128 + xs0));
            bf16x8 va1 = __builtin_bit_cast(bf16x8,
                *(const ushortx8*)(vcb + row * 128 + xs1));
            oacc[dc] = __builtin_amdgcn_mfma_f32_16x16x32_bf16(va0, pb0, oacc[dc], 0, 0, 0);
            oacc[dc] = __builtin_amdgcn_mfma_f32_16x16x32_bf16(va1, pb1, oacc[dc], 0, 0, 0);
        }
        __builtin_amdgcn_s_setprio(0);

        __syncthreads();                 // drains prefetch glds + orders dbuf
        cur ^= 1;
    }

    // partial epilogue: lane-major coalesced dump; combine kernel unpicks it
    const int pidx = (qt * 8 + bh) * NSPLIT + sp;
    float* op = opart + (size_t)pidx * 4096 + wvid * 1024 + lane * 16;
#pragma unroll
    for (int dc = 0; dc < 4; ++dc) *(f32x4*)(op + dc * 4) = oacc[dc];
    if (lhi == 0) {
        float* mlo = mlpart + (size_t)pidx * 128 + wvid * 32 + l16;
        mlo[0]  = m;
        mlo[16] = lsum;
    }
}

// ---------------------------------------------------------------------------
// Combine NSPLIT partials, normalize, transpose, write out twice.
__global__ __launch_bounds__(256) void combine_kernel(
    const float* __restrict__ opart, const float* __restrict__ mlpart,
    float* __restrict__ out)
{
    const int qt = blockIdx.x, bh = blockIdx.y;
    const int b = bh >> 1, h = bh & 1;
    const int t = threadIdx.x, lane = t & 63, w = t >> 6;
    const int l16 = lane & 15, lhi = lane >> 4;
    __shared__ __align__(16) float smT[64][68];

    const int p0 = (qt * 8 + bh) * NSPLIT;
    const float* mlb = mlpart + (size_t)p0 * 128 + w * 32 + l16;
    float m1 = mlb[0],   l1 = mlb[16];
    float m2 = mlb[128], l2 = mlb[128 + 16];
    float M  = fmaxf(m1, m2);
    float c1 = fexp2(m1 - M), c2 = fexp2(m2 - M);
    float inv = 1.f / (l1 * c1 + l2 * c2);
    c1 *= inv; c2 *= inv;

    const float* o1 = opart + (size_t)p0 * 4096 + w * 1024 + lane * 16;
    const float* o2 = o1 + 4096;
#pragma unroll
    for (int dc = 0; dc < 4; ++dc) {
        f32x4 a  = *(const f32x4*)(o1 + dc * 4);
        f32x4 bb = *(const f32x4*)(o2 + dc * 4);
        f32x4 ov = a * c1 + bb * c2;
#pragma unroll
        for (int r = 0; r < 4; ++r)
            smT[dc * 16 + lhi * 4 + r][w * 16 + l16] = ov[r];
    }
    __syncthreads();

    const int d = t >> 2, qq = t & 3;
    size_t ob = (((size_t)(b * 64 + d)) * 2 + h) * 4096 + qt * 64 + qq * 16;
#pragma unroll
    for (int k0 = 0; k0 < 16; k0 += 4) {
        f32x4 vv = *(const f32x4*)(&smT[d][qq * 16 + k0]);
        *(f32x4*)(out + ob + k0) = vv;
        *(f32x4*)(out + ob + OUT_HALF + k0) = vv;
    }
}

// ---------------------------------------------------------------------------
extern "C" void kernel_launch(void* const* d_in, const int* in_sizes, int n_in,
                              void* d_out, int out_size, void* d_ws, size_t ws_size,
                              hipStream_t stream) {
    const float* x  = (const float*)d_in[0];
    const float* wq = (const float*)d_in[1];
    const float* bq = (const float*)d_in[2];
    const float* wk = (const float*)d_in[3];
    const float* bk = (const float*)d_in[4];
    const float* wv = (const float*)d_in[5];
    const float* bv = (const float*)d_in[6];
    const float* pe = (const float*)d_in[7];
    float* out = (float*)d_out;

    char* ws = (char*)d_ws;
    float*    pet   = (float*)ws;                                   // 2 MB
    ushort_t* qw    = (ushort_t*)(ws + (size_t)2  * 1024 * 1024);   // 4 MB
    ushort_t* kw    = (ushort_t*)(ws + (size_t)6  * 1024 * 1024);   // 4 MB
    ushort_t* vw    = (ushort_t*)(ws + (size_t)10 * 1024 * 1024);   // 4 MB
    float*    opart = (float*)(ws + (size_t)14 * 1024 * 1024);      // 16 MB (attn)
    ushort_t* xtb   = (ushort_t*)(ws + (size_t)14 * 1024 * 1024);   // 4 MB (proj, aliases opart)
    float*    mlprt = (float*)(ws + (size_t)30 * 1024 * 1024);      // 0.5 MB (attn)
    ushort_t* wb    = (ushort_t*)(ws + (size_t)30 * 1024 * 1024);   // 96 KB (proj, aliases mlprt)

    hipLaunchKernelGGL(prep_kernel, dim3(1048), dim3(256), 0, stream,
                       pe, wq, wk, wv, pet, wb);
    hipLaunchKernelGGL(xt_kernel, dim3(64, 4), dim3(256), 0, stream, x, xtb);
    hipLaunchKernelGGL(proj_kernel, dim3(32, 4, 3), dim3(256), 0, stream,
                       xtb, wb, bq, bk, bv, pet, qw, kw, vw);
    hipLaunchKernelGGL(attn_kernel, dim3(64, 8, NSPLIT), dim3(256), 0, stream,
                       qw, kw, vw, opart, mlprt);
    hipLaunchKernelGGL(combine_kernel, dim3(64, 8), dim3(256), 0, stream,
                       opart, mlprt, out);
}

// Round 6
// 85.203 us; speedup vs baseline: 2.0511x; 1.3700x over previous
//
#include <hip/hip_runtime.h>
#include <hip/hip_bf16.h>

typedef unsigned short ushort_t;
typedef unsigned int   uint_t;
typedef unsigned short ushortx8 __attribute__((ext_vector_type(8)));
typedef unsigned short ushortx4 __attribute__((ext_vector_type(4)));
typedef unsigned int   uintx4   __attribute__((ext_vector_type(4)));
typedef __bf16        bf16x8   __attribute__((ext_vector_type(8)));
typedef float         f32x4    __attribute__((ext_vector_type(4)));
typedef float         f32x16   __attribute__((ext_vector_type(16)));

#define SCALE_QL (0.29730177875068026f * 1.4426950408889634f) /* 128^-.25 * log2e */
#define OUT_HALF 2097152               /* B*C*H*W elements */
#define NSPLIT   4
#define KT_SPLIT 16                    /* 64 kt tiles / NSPLIT */
#define ML_OFF   131072                /* 512 pidx * 4 wv * 2 s * 32 */

static __device__ __forceinline__ float fexp2(float x) {
    float r; asm("v_exp_f32 %0, %1" : "=v"(r) : "v"(x)); return r;
}
static __device__ __forceinline__ float max3f(float a, float b, float c) {
    float r; asm("v_max3_f32 %0, %1, %2, %3" : "=v"(r) : "v"(a), "v"(b), "v"(c));
    return r;
}
static __device__ __forceinline__ unsigned cvtpk_bf16(float lo, float hi) {
    unsigned r;
    asm("v_cvt_pk_bf16_f32 %0, %1, %2" : "=v"(r) : "v"(lo), "v"(hi));
    return r;
}
static __device__ __forceinline__ void pswap(unsigned& a, unsigned& b) {
    asm("v_permlane32_swap_b32 %0, %1" : "+v"(a), "+v"(b));
}
static __device__ __forceinline__ ushort_t bf16u(float f) {
    __hip_bfloat16 h = __float2bfloat16(f);
    return __builtin_bit_cast(ushort_t, h);
}
static __device__ __forceinline__ float bflo(unsigned u) {
    return __builtin_bit_cast(float, u << 16);
}
static __device__ __forceinline__ float bfhi(unsigned u) {
    return __builtin_bit_cast(float, u & 0xffff0000u);
}
static __device__ __forceinline__ void glds16(const void* g, void* l) {
    __builtin_amdgcn_global_load_lds(
        (const __attribute__((address_space(1))) unsigned int*)g,
        (__attribute__((address_space(3))) unsigned int*)l, 16, 0, 0);
}

// ---------------------------------------------------------------------------
// prep: pe [n][d][h] -> pet [h][n][d] f32;  wq/wk/wv f32 -> wb bf16 with
// row-local 16B-chunk xor swizzle (chunk ^= o&15) baked in.
__global__ __launch_bounds__(256) void prep_kernel(
    const float* __restrict__ pe,
    const float* __restrict__ wq, const float* __restrict__ wk,
    const float* __restrict__ wv,
    float* __restrict__ pet, ushort_t* __restrict__ wb)
{
    const int bid = blockIdx.x, t = threadIdx.x;
    if (bid < 1024) {
        int idx = bid * 256 + t;
        float2 p2 = *(const float2*)(pe + (size_t)idx * 2);
        pet[idx]                     = p2.x;
        pet[(size_t)4096 * 64 + idx] = p2.y;
        return;
    }
    const int b2 = bid - 1024;                 // 0..23
    const int p  = b2 >> 3;
    const float* w = (p == 0) ? wq : (p == 1) ? wk : wv;
    const int cid = (b2 & 7) * 256 + t;        // 16B-chunk id 0..2047
    const int o = cid >> 4, chunk = cid & 15;
    float4 f0 = *(const float4*)(w + o * 128 + chunk * 8);
    float4 f1 = *(const float4*)(w + o * 128 + chunk * 8 + 4);
    ushortx8 u;
    u[0] = bf16u(f0.x); u[1] = bf16u(f0.y); u[2] = bf16u(f0.z); u[3] = bf16u(f0.w);
    u[4] = bf16u(f1.x); u[5] = bf16u(f1.y); u[6] = bf16u(f1.z); u[7] = bf16u(f1.w);
    *(ushortx8*)(wb + p * 16384 + o * 128 + ((chunk ^ (o & 15)) << 3)) = u;
}

// ---------------------------------------------------------------------------
// x [b][c=128][n] f32 -> xtb [b][n][c=128] bf16, chunk-swizzled per row.
__global__ __launch_bounds__(256) void xt_kernel(const float* __restrict__ x,
                                                 ushort_t* __restrict__ xtb)
{
    const int nt = blockIdx.x, b = blockIdx.y;
    __shared__ __align__(16) ushort_t xs[128][68];
    const int t = threadIdx.x;
    const int cg = t >> 4, n0 = (t & 15) * 4;
#pragma unroll
    for (int i = 0; i < 8; ++i) {
        int c = i * 16 + cg;
        float4 f = *(const float4*)(x + ((size_t)(b * 128 + c)) * 4096 + nt * 64 + n0);
        ushortx4 u;
        u[0] = bf16u(f.x); u[1] = bf16u(f.y); u[2] = bf16u(f.z); u[3] = bf16u(f.w);
        *(ushortx4*)(&xs[c][n0]) = u;
    }
    __syncthreads();
    const int n = t >> 2;
    ushort_t* dst = xtb + ((size_t)b * 4096 + nt * 64 + n) * 128;
#pragma unroll
    for (int j = 0; j < 4; ++j) {
        int chunk = (t & 3) * 4 + j;
        ushortx8 u;
#pragma unroll
        for (int e = 0; e < 8; ++e) u[e] = xs[chunk * 8 + e][n];
        *(ushortx8*)(dst + ((chunk ^ (n & 15)) << 3)) = u;
    }
}

// ---------------------------------------------------------------------------
// MFMA projection: per block 128 outputs x 128 tokens, K=128.
// grid (32 ntile, 4 b, 3 p), 256 thr (4 waves, each 32 output rows).
__global__ __launch_bounds__(256, 2) void proj_kernel(
    const ushort_t* __restrict__ xtb, const ushort_t* __restrict__ wb,
    const float* __restrict__ bq, const float* __restrict__ bk,
    const float* __restrict__ bv, const float* __restrict__ pet,
    ushort_t* __restrict__ qw, ushort_t* __restrict__ kw,
    ushort_t* __restrict__ vw)
{
    const int ntl = blockIdx.x;        // 128-token tile
    const int b = blockIdx.y, p = blockIdx.z;
    __shared__ __align__(16) ushort_t xt[16384];   // [n128][c128] swizzled
    __shared__ __align__(16) ushort_t wt[16384];   // [o128][c128] swizzled
    const int t = threadIdx.x, lane = t & 63;
    const int wv_ = __builtin_amdgcn_readfirstlane(t >> 6);
    const int l16 = lane & 15, lhi = lane >> 4;

    const ushort_t* xsrc = xtb + ((size_t)b * 4096 + ntl * 128) * 128;
    const ushort_t* wsrc = wb + p * 16384;
#pragma unroll
    for (int j = 0; j < 8; ++j) {
        int row = wv_ * 32 + j * 4;
        glds16(xsrc + row * 128 + lane * 8, xt + row * 128);
        glds16(wsrc + row * 128 + lane * 8, wt + row * 128);
    }

    const float* bias = (p == 0) ? bq : (p == 1) ? bk : bv;
    f32x4 bias4[2];
    bias4[0] = *(const f32x4*)(bias + wv_ * 32 + lhi * 4);
    bias4[1] = *(const f32x4*)(bias + wv_ * 32 + 16 + lhi * 4);
    f32x4 acc[2][8];
#pragma unroll
    for (int mf = 0; mf < 2; ++mf)
#pragma unroll
        for (int nf = 0; nf < 8; ++nf) acc[mf][nf] = bias4[mf];

    __syncthreads();

    const char* xbp = (const char*)xt;
    const char* wbp = (const char*)wt;
#pragma unroll
    for (int ks = 0; ks < 4; ++ks) {
        bf16x8 af[2];
#pragma unroll
        for (int mf = 0; mf < 2; ++mf) {
            int row = wv_ * 32 + mf * 16 + l16;
            af[mf] = __builtin_bit_cast(bf16x8, *(const ushortx8*)(
                wbp + row * 256 + ((((ks * 4 + lhi) ^ l16) & 15) << 4)));
        }
#pragma unroll
        for (int nf = 0; nf < 8; ++nf) {
            int row = nf * 16 + l16;
            bf16x8 bfr = __builtin_bit_cast(bf16x8, *(const ushortx8*)(
                xbp + row * 256 + ((((ks * 4 + lhi) ^ l16) & 15) << 4)));
            acc[0][nf] = __builtin_amdgcn_mfma_f32_16x16x32_bf16(af[0], bfr, acc[0][nf], 0, 0, 0);
            acc[1][nf] = __builtin_amdgcn_mfma_f32_16x16x32_bf16(af[1], bfr, acc[1][nf], 0, 0, 0);
        }
    }

    const int nbase = ntl * 128;
    if (p == 2) {                      // V -> d-major [bh][d][n]
#pragma unroll
        for (int mf = 0; mf < 2; ++mf) {
            int o = wv_ * 32 + mf * 16 + lhi * 4;
            int h = o >> 6, d = o & 63;
            ushort_t* vb = vw + (((size_t)(b * 2 + h) * 64 + d)) * 4096 + nbase + l16;
#pragma unroll
            for (int nf = 0; nf < 8; ++nf)
#pragma unroll
                for (int r = 0; r < 4; ++r)
                    vb[(size_t)r * 4096 + nf * 16] = bf16u(acc[mf][nf][r]);
        }
    } else if (p == 0) {               // Q: +pe, *scale, token-major
#pragma unroll
        for (int mf = 0; mf < 2; ++mf) {
            int o = wv_ * 32 + mf * 16 + lhi * 4;
            int h = o >> 6, d = o & 63;
#pragma unroll
            for (int nf = 0; nf < 8; ++nf) {
                int n = nbase + nf * 16 + l16;
                f32x4 pe4 = *(const f32x4*)(pet + ((size_t)h * 4096 + n) * 64 + d);
                f32x4 q4 = (acc[mf][nf] + pe4) * SCALE_QL;
                ushortx4 s;
                s[0] = bf16u(q4[0]); s[1] = bf16u(q4[1]);
                s[2] = bf16u(q4[2]); s[3] = bf16u(q4[3]);
                *(ushortx4*)(qw + ((size_t)(b * 2 + h) * 4096 + n) * 64 + d) = s;
            }
        }
    } else {                           // K: token-major
#pragma unroll
        for (int mf = 0; mf < 2; ++mf) {
            int o = wv_ * 32 + mf * 16 + lhi * 4;
            int h = o >> 6, d = o & 63;
#pragma unroll
            for (int nf = 0; nf < 8; ++nf) {
                int n = nbase + nf * 16 + l16;
                f32x4 k4 = acc[mf][nf];
                ushortx4 s;
                s[0] = bf16u(k4[0]); s[1] = bf16u(k4[1]);
                s[2] = bf16u(k4[2]); s[3] = bf16u(k4[3]);
                *(ushortx4*)(kw + ((size_t)(b * 2 + h) * 4096 + n) * 64 + d) = s;
            }
        }
    }
}

// ---------------------------------------------------------------------------
// Flash attention, 32x32 MFMA, swapped (S^T = K*Q), 64 q per wave.
// P: C-frag -> PV B-frag fully in-register via cvt_pk + permlane32_swap.
// K,V double-buffered LDS, glds16 prefetch, 1 barrier/iter, defer-max.
// grid (16 qtile(256q), 8 bh, NSPLIT), 256 thr (4 waves x 64 q).
__global__ __launch_bounds__(256, 2) void attn_kernel(
    const ushort_t* __restrict__ qw, const ushort_t* __restrict__ kw,
    const ushort_t* __restrict__ vw, uint_t* __restrict__ opart,
    float* __restrict__ mlpart)
{
    const int qt = blockIdx.x, bh = blockIdx.y, sp = blockIdx.z;
    const int t = threadIdx.x, lane = t & 63;
    const int wv = t >> 6;
    const int l31 = lane & 31, hi = lane >> 5;

    __shared__ __align__(16) ushort_t Kt[2 * 64 * 64];   // dbuf [key][d] swz
    __shared__ __align__(16) ushort_t Vt[2 * 64 * 64];   // dbuf [d][key] swz

    // Q B-frags [slot][ks]: lane holds Q[q = qb+s*32+l31][d = ks*16+hi*8 ..+8]
    const int qb = qt * 256 + wv * 64;
    bf16x8 qf[2][4];
#pragma unroll
    for (int s = 0; s < 2; ++s)
#pragma unroll
        for (int ks = 0; ks < 4; ++ks)
            qf[s][ks] = __builtin_bit_cast(bf16x8, *(const ushortx8*)(
                qw + ((size_t)bh * 4096 + qb + s * 32 + l31) * 64 + ks * 16 + hi * 8));

    const ushort_t* kgb = kw + ((size_t)bh * 4096) * 64;
    const ushort_t* vgb = vw + ((size_t)bh * 64) * 4096;

    // staging: wave covers rows [wv*16, wv*16+16); source pre-XOR-swizzled.
    const int srow = lane >> 3, c7 = lane & 7;
    const int rb = wv * 16;
    const int swz = (c7 ^ srow) << 3;
    const size_t koff0 = (size_t)(rb + srow) * 64 + swz;
    const size_t koff1 = (size_t)(rb + 8 + srow) * 64 + swz;
    const size_t voff0 = (size_t)(rb + srow) * 4096 + swz;
    const size_t voff1 = (size_t)(rb + 8 + srow) * 4096 + swz;

    const f32x16 z16 = {0,0,0,0,0,0,0,0,0,0,0,0,0,0,0,0};
    f32x16 oa00 = z16, oa01 = z16, oa10 = z16, oa11 = z16;  // [slot][dt]
    float m0 = -1e30f, m1 = -1e30f, ls0 = 0.f, ls1 = 0.f;

    const int kt0 = sp * KT_SPLIT;

#define STAGE(buf, ktb)                                                       \
    {                                                                         \
        const ushort_t* kg = kgb + (size_t)(ktb) * 4096;                      \
        const ushort_t* vg = vgb + (size_t)(ktb) * 64;                        \
        ushort_t* kd = Kt + (buf) * 4096;                                     \
        ushort_t* vd = Vt + (buf) * 4096;                                     \
        glds16(kg + koff0, kd + (size_t)rb * 64);                             \
        glds16(kg + koff1, kd + (size_t)(rb + 8) * 64);                       \
        glds16(vg + voff0, vd + (size_t)rb * 64);                             \
        glds16(vg + voff1, vd + (size_t)(rb + 8) * 64);                       \
    }

    STAGE(0, kt0)
    __syncthreads();

    const int sw7 = l31 & 7;
    int cur = 0;
    for (int it = 0; it < KT_SPLIT; ++it) {
        const int itn = (it + 1 < KT_SPLIT) ? it + 1 : it;
        STAGE(cur ^ 1, kt0 + itn)

        const char* kc = (const char*)(Kt + cur * 4096);
        const char* vc = (const char*)(Vt + cur * 4096);

#pragma unroll
        for (int c = 0; c < 2; ++c) {            // 32-key chain
            const int kbase = (c * 32 + l31) * 128;
            bf16x8 kf[4];
#pragma unroll
            for (int ks = 0; ks < 4; ++ks)
                kf[ks] = __builtin_bit_cast(bf16x8, *(const ushortx8*)(
                    kc + kbase + (((ks * 2 + hi) ^ sw7) << 4)));

            f32x16 s0 = z16, s1 = z16;
            __builtin_amdgcn_s_setprio(1);
#pragma unroll
            for (int ks = 0; ks < 4; ++ks) {
                s0 = __builtin_amdgcn_mfma_f32_32x32x16_bf16(kf[ks], qf[0][ks], s0, 0, 0, 0);
                s1 = __builtin_amdgcn_mfma_f32_32x32x16_bf16(kf[ks], qf[1][ks], s1, 0, 0, 0);
            }
            __builtin_amdgcn_s_setprio(0);

            bf16x8 pf0a, pf0b, pf1a, pf1b;
#define SM_CHAIN(SV, MREG, LREG, OA0, OA1, PFA, PFB)                          \
            {                                                                 \
                float a0 = max3f(SV[0], SV[1], SV[2]);                        \
                float a1 = max3f(SV[3], SV[4], SV[5]);                        \
                float a2 = max3f(SV[6], SV[7], SV[8]);                        \
                float a3 = max3f(SV[9], SV[10], SV[11]);                      \
                float a4 = max3f(SV[12], SV[13], SV[14]);                     \
                float smax = fmaxf(max3f(a0, a1, a2), max3f(a3, a4, SV[15])); \
                smax = fmaxf(smax, __shfl_xor(smax, 32, 64));                 \
                if (!__all(smax - MREG <= 8.0f)) {                            \
                    float mnew = fmaxf(MREG, smax);                           \
                    float corr = fexp2(MREG - mnew);                          \
                    MREG = mnew; LREG *= corr;                                \
                    OA0 *= corr; OA1 *= corr;                                 \
                }                                                             \
                float p[16], psum = 0.f;                                      \
                _Pragma("unroll")                                             \
                for (int r = 0; r < 16; ++r) {                                \
                    p[r] = fexp2(SV[r] - MREG); psum += p[r];                 \
                }                                                             \
                psum += __shfl_xor(psum, 32, 64);                             \
                LREG += psum;                                                 \
                unsigned c0 = cvtpk_bf16(p[0], p[1]);                         \
                unsigned c1 = cvtpk_bf16(p[2], p[3]);                         \
                unsigned c2 = cvtpk_bf16(p[4], p[5]);                         \
                unsigned c3 = cvtpk_bf16(p[6], p[7]);                         \
                unsigned c4 = cvtpk_bf16(p[8], p[9]);                         \
                unsigned c5 = cvtpk_bf16(p[10], p[11]);                       \
                unsigned c6 = cvtpk_bf16(p[12], p[13]);                       \
                unsigned c7x = cvtpk_bf16(p[14], p[15]);                      \
                pswap(c0, c2); pswap(c1, c3); pswap(c4, c6); pswap(c5, c7x);  \
                { uintx4 u; u[0] = c0; u[1] = c1; u[2] = c2; u[3] = c3;       \
                  PFA = __builtin_bit_cast(bf16x8, u); }                      \
                { uintx4 u; u[0] = c4; u[1] = c5; u[2] = c6; u[3] = c7x;      \
                  PFB = __builtin_bit_cast(bf16x8, u); }                      \
            }
            SM_CHAIN(s0, m0, ls0, oa00, oa01, pf0a, pf0b)
            SM_CHAIN(s1, m1, ls1, oa10, oa11, pf1a, pf1b)

            // O^T += V^T P^T
            __builtin_amdgcn_s_setprio(1);
            {
                const int vb0 = (l31) * 128;
                bf16x8 vf0 = __builtin_bit_cast(bf16x8, *(const ushortx8*)(
                    vc + vb0 + ((((c * 2 + 0) * 2 + hi) ^ sw7) << 4)));
                bf16x8 vf1 = __builtin_bit_cast(bf16x8, *(const ushortx8*)(
                    vc + vb0 + ((((c * 2 + 1) * 2 + hi) ^ sw7) << 4)));
                oa00 = __builtin_amdgcn_mfma_f32_32x32x16_bf16(vf0, pf0a, oa00, 0, 0, 0);
                oa00 = __builtin_amdgcn_mfma_f32_32x32x16_bf16(vf1, pf0b, oa00, 0, 0, 0);
                oa10 = __builtin_amdgcn_mfma_f32_32x32x16_bf16(vf0, pf1a, oa10, 0, 0, 0);
                oa10 = __builtin_amdgcn_mfma_f32_32x32x16_bf16(vf1, pf1b, oa10, 0, 0, 0);
            }
            {
                const int vb1 = (32 + l31) * 128;
                bf16x8 vf0 = __builtin_bit_cast(bf16x8, *(const ushortx8*)(
                    vc + vb1 + ((((c * 2 + 0) * 2 + hi) ^ sw7) << 4)));
                bf16x8 vf1 = __builtin_bit_cast(bf16x8, *(const ushortx8*)(
                    vc + vb1 + ((((c * 2 + 1) * 2 + hi) ^ sw7) << 4)));
                oa01 = __builtin_amdgcn_mfma_f32_32x32x16_bf16(vf0, pf0a, oa01, 0, 0, 0);
                oa01 = __builtin_amdgcn_mfma_f32_32x32x16_bf16(vf1, pf0b, oa01, 0, 0, 0);
                oa11 = __builtin_amdgcn_mfma_f32_32x32x16_bf16(vf0, pf1a, oa11, 0, 0, 0);
                oa11 = __builtin_amdgcn_mfma_f32_32x32x16_bf16(vf1, pf1b, oa11, 0, 0, 0);
            }
            __builtin_amdgcn_s_setprio(0);
        }

        __syncthreads();                 // drains prefetch glds + orders dbuf
        cur ^= 1;
    }

    // epilogue: bf16-pack unnormalized O partials, coalesced dump
    const int pidx = (qt * 8 + bh) * NSPLIT + sp;
#define STORE_OA(OA, S, DT)                                                   \
    {                                                                         \
        uintx4 u0, u1;                                                        \
        u0[0] = cvtpk_bf16(OA[0], OA[1]);  u0[1] = cvtpk_bf16(OA[2], OA[3]);  \
        u0[2] = cvtpk_bf16(OA[4], OA[5]);  u0[3] = cvtpk_bf16(OA[6], OA[7]);  \
        u1[0] = cvtpk_bf16(OA[8], OA[9]);  u1[1] = cvtpk_bf16(OA[10], OA[11]);\
        u1[2] = cvtpk_bf16(OA[12], OA[13]);u1[3] = cvtpk_bf16(OA[14], OA[15]);\
        uint_t* dst = opart +                                                 \
            ((((size_t)pidx * 4 + wv) * 2 + (S)) * 2 + (DT)) * 512 + lane * 8;\
        *(uintx4*)dst = u0; *(uintx4*)(dst + 4) = u1;                         \
    }
    STORE_OA(oa00, 0, 0) STORE_OA(oa01, 0, 1)
    STORE_OA(oa10, 1, 0) STORE_OA(oa11, 1, 1)

    if (hi == 0) {
        int i0 = ((pidx * 4 + wv) * 2 + 0) * 32 + l31;
        int i1 = ((pidx * 4 + wv) * 2 + 1) * 32 + l31;
        mlpart[i0] = m0; mlpart[ML_OFF + i0] = ls0;
        mlpart[i1] = m1; mlpart[ML_OFF + i1] = ls1;
    }
}

// ---------------------------------------------------------------------------
// Combine NSPLIT partials, normalize, write out twice. grid (16 qt, 8 bh).
__global__ __launch_bounds__(256) void combine_kernel(
    const uint_t* __restrict__ opart, const float* __restrict__ mlpart,
    float* __restrict__ out)
{
    const int qt = blockIdx.x, bh = blockIdx.y;
    const int b = bh >> 1, h = bh & 1;
    const int t = threadIdx.x, lane = t & 63, wv = t >> 6;
    const int l31 = lane & 31, hi = lane >> 5;
    const int pbase = (qt * 8 + bh) * NSPLIT;
    const int dtbl[8] = {0, 2, 8, 10, 16, 18, 24, 26};

#pragma unroll
    for (int s = 0; s < 2; ++s) {
        float mv[4], lv[4];
#pragma unroll
        for (int sp = 0; sp < 4; ++sp) {
            int idx = (((pbase + sp) * 4 + wv) * 2 + s) * 32 + l31;
            mv[sp] = mlpart[idx];
            lv[sp] = mlpart[ML_OFF + idx];
        }
        float M = fmaxf(fmaxf(mv[0], mv[1]), fmaxf(mv[2], mv[3]));
        float wn[4], den = 0.f;
#pragma unroll
        for (int sp = 0; sp < 4; ++sp) {
            wn[sp] = fexp2(mv[sp] - M);
            den += lv[sp] * wn[sp];
        }
        float inv = 1.f / den;

        const int q = qt * 256 + wv * 64 + s * 32 + l31;
#pragma unroll
        for (int dt = 0; dt < 2; ++dt) {
            float acc[16];
#pragma unroll
            for (int i = 0; i < 16; ++i) acc[i] = 0.f;
#pragma unroll
            for (int sp = 0; sp < 4; ++sp) {
                const uint_t* src = opart +
                    ((((size_t)(pbase + sp) * 4 + wv) * 2 + s) * 2 + dt) * 512 + lane * 8;
                uintx4 a = *(const uintx4*)src;
                uintx4 b2 = *(const uintx4*)(src + 4);
                float w_ = wn[sp] * inv;
#pragma unroll
                for (int j = 0; j < 4; ++j) {
                    acc[2 * j]     += w_ * bflo(a[j]);
                    acc[2 * j + 1] += w_ * bfhi(a[j]);
                    acc[8 + 2 * j] += w_ * bflo(b2[j]);
                    acc[9 + 2 * j] += w_ * bfhi(b2[j]);
                }
            }
#pragma unroll
            for (int j = 0; j < 8; ++j) {
                int d = dt * 32 + 4 * hi + dtbl[j];
                size_t o0 = ((size_t)(b * 128 + d * 2 + h)) * 4096 + q;
                out[o0] = acc[2 * j];
                out[o0 + OUT_HALF] = acc[2 * j];
                size_t o1 = o0 + 2 * 4096;
                out[o1] = acc[2 * j + 1];
                out[o1 + OUT_HALF] = acc[2 * j + 1];
            }
        }
    }
}

// ---------------------------------------------------------------------------
extern "C" void kernel_launch(void* const* d_in, const int* in_sizes, int n_in,
                              void* d_out, int out_size, void* d_ws, size_t ws_size,
                              hipStream_t stream) {
    const float* x  = (const float*)d_in[0];
    const float* wq = (const float*)d_in[1];
    const float* bq = (const float*)d_in[2];
    const float* wk = (const float*)d_in[3];
    const float* bk = (const float*)d_in[4];
    const float* wv = (const float*)d_in[5];
    const float* bv = (const float*)d_in[6];
    const float* pe = (const float*)d_in[7];
    float* out = (float*)d_out;

    char* ws = (char*)d_ws;
    float*    pet   = (float*)ws;                                   // 2 MB
    ushort_t* qw    = (ushort_t*)(ws + (size_t)2  * 1024 * 1024);   // 4 MB
    ushort_t* kw    = (ushort_t*)(ws + (size_t)6  * 1024 * 1024);   // 4 MB
    ushort_t* vw    = (ushort_t*)(ws + (size_t)10 * 1024 * 1024);   // 4 MB
    uint_t*   opart = (uint_t*)(ws + (size_t)14 * 1024 * 1024);     // 16 MB (attn)
    ushort_t* xtb   = (ushort_t*)(ws + (size_t)14 * 1024 * 1024);   // 4 MB (proj, aliases opart)
    float*    mlprt = (float*)(ws + (size_t)30 * 1024 * 1024);      // 1 MB (attn)
    ushort_t* wb    = (ushort_t*)(ws + (size_t)30 * 1024 * 1024);   // 96 KB (proj, aliases mlprt)

    hipLaunchKernelGGL(prep_kernel, dim3(1048), dim3(256), 0, stream,
                       pe, wq, wk, wv, pet, wb);
    hipLaunchKernelGGL(xt_kernel, dim3(64, 4), dim3(256), 0, stream, x, xtb);
    hipLaunchKernelGGL(proj_kernel, dim3(32, 4, 3), dim3(256), 0, stream,
                       xtb, wb, bq, bk, bv, pet, qw, kw, vw);
    hipLaunchKernelGGL(attn_kernel, dim3(16, 8, NSPLIT), dim3(256), 0, stream,
                       qw, kw, vw, opart, mlprt);
    hipLaunchKernelGGL(combine_kernel, dim3(16, 8), dim3(256), 0, stream,
                       opart, mlprt, out);
}